// Round 4
// baseline (10699.177 us; speedup 1.0000x reference)
//
#include <hip/hip_runtime.h>
#include <stdint.h>

// MambaBlock: DIM=1024, BATCH=8, SEQ=4096.
//   inp  = x @ W_in^T + b_in                  (fp32, parked in d_out)
//   gate = sigmoid(inp @ W_gate^T + b_gate)   (bf16 in ws)
//   u    = inp @ B^T                          (bf16 in ws)
//   scan: s_t = g*tanh(s_{t-1}@A^T + u_t) + (1-g)*inp_t   (fp32, tagged-granule LLC exchange)
//   out  = states @ W_out^T + b_out           (fp32 -> d_out)
//
// Scan v5 = v4 + A in AGPRs.
//   v3/v4's register pins were defeated (VGPR_Count=88 < the 128 A needs), so A
//   was re-fetched from L2/scratch every step: ~32KB/wave/step = ~21 TB/s
//   aggregate L2 pressure AND latency on the FMA chain. v5 stashes the 128
//   per-lane A values in AGPRs via the "a" inline-asm constraint
//   (v_accvgpr_write_b32 once at init; v_accvgpr_read_b32 per use). The
//   allocator tracks these natively (agpr_count accounted, no clobber games),
//   and on gfx950's unified RF this costs zero occupancy at 1 wave/SIMD.
//   Everything else is identical to v4: cooperative quarter-poll, LDS
//   broadcast (double-buffered), tagged granules (epoch tag (t&7)|8 in the low
//   float's mantissa nibble, memset clears stale tags), XCD-local batches,
//   packed tail reduction.

#define D 1024
#define NBATCH 8
#define SEQ 4096
#define NROWS 32768  // NBATCH*SEQ

static constexpr size_t GATE_BYTES  = (size_t)NROWS * D * 2;          // 64 MiB bf16
static constexpr size_t U_BYTES     = (size_t)NROWS * D * 2;          // 64 MiB bf16
static constexpr size_t SLICE_BYTES = (size_t)SEQ * NBATCH * D * 4;   // 128 MiB fp32

typedef float f32x2 __attribute__((ext_vector_type(2)));

__device__ __forceinline__ float bf2f(uint16_t h) {
  uint32_t u = ((uint32_t)h) << 16;
  return __builtin_bit_cast(float, u);
}
__device__ __forceinline__ uint16_t f2bf(float f) {
  uint32_t u = __builtin_bit_cast(uint32_t, f);
  u = u + 0x7fffu + ((u >> 16) & 1u);   // RNE
  return (uint16_t)(u >> 16);
}

// branch-free tanh: 1 - 2/(e^{2x}+1); saturates correctly at +-1 via inf/0.
__device__ __forceinline__ float fast_tanh(float x) {
  const float e = __expf(2.0f * x);
  return 1.0f - 2.0f / (e + 1.0f);
}

// ---------------- GEMM 1: inp = x @ W_in^T + b_in (fp32 out) ----------------
__global__ __launch_bounds__(256) void k_gemm_in(
    const float* __restrict__ X, const float* __restrict__ W,
    const float* __restrict__ bias, float* __restrict__ Y) {
  __shared__ float Xs[16][68];
  __shared__ float Ws[16][68];
  const int tid = threadIdx.x;
  const int m0 = blockIdx.y << 6, n0 = blockIdx.x << 6;
  const int tx = tid & 15, ty = tid >> 4;
  const int lr = tid >> 2, lk = (tid & 3) << 2;
  float acc[4][4] = {};
  const float* xp = X + (size_t)(m0 + lr) * D + lk;
  const float* wp = W + (size_t)(n0 + lr) * D + lk;
  for (int k0 = 0; k0 < D; k0 += 16) {
    float4 xv = *(const float4*)(xp + k0);
    float4 wv = *(const float4*)(wp + k0);
    __syncthreads();
    Xs[lk + 0][lr] = xv.x; Xs[lk + 1][lr] = xv.y; Xs[lk + 2][lr] = xv.z; Xs[lk + 3][lr] = xv.w;
    Ws[lk + 0][lr] = wv.x; Ws[lk + 1][lr] = wv.y; Ws[lk + 2][lr] = wv.z; Ws[lk + 3][lr] = wv.w;
    __syncthreads();
#pragma unroll
    for (int k = 0; k < 16; ++k) {
      float4 av = *(const float4*)&Xs[k][tx << 2];
      float4 bv = *(const float4*)&Ws[k][ty << 2];
      const float aa[4] = {av.x, av.y, av.z, av.w};
      const float bb[4] = {bv.x, bv.y, bv.z, bv.w};
#pragma unroll
      for (int i = 0; i < 4; ++i)
#pragma unroll
        for (int jj = 0; jj < 4; ++jj) acc[i][jj] += aa[i] * bb[jj];
    }
  }
  const int nc = n0 + (ty << 2);
#pragma unroll
  for (int i = 0; i < 4; ++i) {
    const int row = m0 + (tx << 2) + i;
    float4 o;
    o.x = acc[i][0] + bias[nc + 0];
    o.y = acc[i][1] + bias[nc + 1];
    o.z = acc[i][2] + bias[nc + 2];
    o.w = acc[i][3] + bias[nc + 3];
    *(float4*)&Y[(size_t)row * D + nc] = o;
  }
}

// ------- GEMM 2 (fused): gate = sigmoid(inp@Wg^T + bg), u = inp@B^T (bf16 out) -------
__global__ __launch_bounds__(256) void k_gemm_gate_u(
    const float* __restrict__ X, const float* __restrict__ Wg,
    const float* __restrict__ bg, const float* __restrict__ Bu,
    uint16_t* __restrict__ G, uint16_t* __restrict__ U) {
  __shared__ float Xs[16][68];
  __shared__ float Wgs[16][68];
  __shared__ float Wus[16][68];
  const int tid = threadIdx.x;
  const int m0 = blockIdx.y << 6, n0 = blockIdx.x << 6;
  const int tx = tid & 15, ty = tid >> 4;
  const int lr = tid >> 2, lk = (tid & 3) << 2;
  float accg[4][4] = {}, accu[4][4] = {};
  const float* xp = X + (size_t)(m0 + lr) * D + lk;
  const float* wgp = Wg + (size_t)(n0 + lr) * D + lk;
  const float* wup = Bu + (size_t)(n0 + lr) * D + lk;
  for (int k0 = 0; k0 < D; k0 += 16) {
    float4 xv = *(const float4*)(xp + k0);
    float4 gv = *(const float4*)(wgp + k0);
    float4 uv = *(const float4*)(wup + k0);
    __syncthreads();
    Xs[lk + 0][lr] = xv.x; Xs[lk + 1][lr] = xv.y; Xs[lk + 2][lr] = xv.z; Xs[lk + 3][lr] = xv.w;
    Wgs[lk + 0][lr] = gv.x; Wgs[lk + 1][lr] = gv.y; Wgs[lk + 2][lr] = gv.z; Wgs[lk + 3][lr] = gv.w;
    Wus[lk + 0][lr] = uv.x; Wus[lk + 1][lr] = uv.y; Wus[lk + 2][lr] = uv.z; Wus[lk + 3][lr] = uv.w;
    __syncthreads();
#pragma unroll
    for (int k = 0; k < 16; ++k) {
      float4 av = *(const float4*)&Xs[k][tx << 2];
      float4 g4 = *(const float4*)&Wgs[k][ty << 2];
      float4 u4 = *(const float4*)&Wus[k][ty << 2];
      const float aa[4] = {av.x, av.y, av.z, av.w};
      const float gg[4] = {g4.x, g4.y, g4.z, g4.w};
      const float uu[4] = {u4.x, u4.y, u4.z, u4.w};
#pragma unroll
      for (int i = 0; i < 4; ++i)
#pragma unroll
        for (int jj = 0; jj < 4; ++jj) {
          accg[i][jj] += aa[i] * gg[jj];
          accu[i][jj] += aa[i] * uu[jj];
        }
    }
  }
  const int nc = n0 + (ty << 2);
#pragma unroll
  for (int i = 0; i < 4; ++i) {
    const int row = m0 + (tx << 2) + i;
    ushort4 og, ou;
    {
      float z0 = accg[i][0] + bg[nc + 0], z1 = accg[i][1] + bg[nc + 1];
      float z2 = accg[i][2] + bg[nc + 2], z3 = accg[i][3] + bg[nc + 3];
      og.x = f2bf(1.0f / (1.0f + __expf(-z0)));
      og.y = f2bf(1.0f / (1.0f + __expf(-z1)));
      og.z = f2bf(1.0f / (1.0f + __expf(-z2)));
      og.w = f2bf(1.0f / (1.0f + __expf(-z3)));
    }
    ou.x = f2bf(accu[i][0]); ou.y = f2bf(accu[i][1]);
    ou.z = f2bf(accu[i][2]); ou.w = f2bf(accu[i][3]);
    *(ushort4*)&G[(size_t)row * D + nc] = og;
    *(ushort4*)&U[(size_t)row * D + nc] = ou;
  }
}

// ---------------- Scan v5: cooperative poll + LDS broadcast + AGPR-resident A ----------------
// LDS index padding: granule g -> g + g/16 (breaks 8B-stride bank alias).
__device__ __forceinline__ int pidx(int g) { return g + (g >> 4); }

__global__ __launch_bounds__(256, 1)
void k_scan(
    const float* __restrict__ A, const float* __restrict__ inp,
    const uint16_t* __restrict__ gate, const uint16_t* __restrict__ u,
    float* __restrict__ slice) {
  __shared__ f32x2 Ss[2][544];   // 512 granules + pad, double-buffered (8.7 KB)
  const int tid = threadIdx.x;
  const int w = tid >> 6, l = tid & 63;
  const int b = blockIdx.x & 7;        // batch: XCD-local (block i -> XCD i%8)
  const int widx = blockIdx.x >> 3;    // 0..31 within batch
  const int j0 = (widx << 5) + (w << 3);  // wave's 8 output cols

  // A fragments -> AGPRs. ar[k*16 + c*2 + {0,1}] = A[j0+c][128k + 2l + {0,1}].
  // The "a" constraint makes the allocator place these in the AGPR file
  // (compiler-tracked; zero per-step memory traffic, zero VGPR pressure).
  float ar[128];
#pragma unroll
  for (int k = 0; k < 8; ++k)
#pragma unroll
    for (int c = 0; c < 8; ++c) {
      const float2 t2 = *(const float2*)&A[(size_t)(j0 + c) * D + (k << 7) + (l << 1)];
      asm volatile("v_accvgpr_write_b32 %0, %1"
                   : "=a"(ar[(k << 4) + (c << 1)]) : "v"(t2.x));
      asm volatile("v_accvgpr_write_b32 %0, %1"
                   : "=a"(ar[(k << 4) + (c << 1) + 1]) : "v"(t2.y));
    }

  unsigned long long* slice8 = (unsigned long long*)slice;
  const int jc = j0 + l;               // valid for l<8: lane's output column
  const int g0 = (w << 7) + l;         // this wave's poll quarter: granules g0, g0+64
  const int pg0 = pidx(g0), pg1 = pidx(g0 + 64);

  for (int t = 0; t < SEQ; ++t) {
    // prefetch this step's gate/u/inp (cached loads, issued before the spin)
    float pg = 0.f, pu = 0.f, pi = 0.f;
    if (l < 8) {
      const size_t ridx = ((size_t)(b << 12) + t) * D + jc;
      pg = bf2f(gate[ridx]);
      pu = bf2f(u[ridx]);
      pi = inp[ridx];
    }
    asm volatile("" : "+v"(pg), "+v"(pu), "+v"(pi));

    float f = 0.f;
    if (t > 0) {
      // ---- cooperative poll: this wave owns granules [128w, 128w+128) ----
      const unsigned long long* src8 =
          slice8 + (((size_t)(t - 1) * NBATCH + b) << 9);
      const uint32_t tagv = (uint32_t)(((t - 1) & 7) | 8);
      unsigned long long v0, v1;
      while (true) {
        v0 = __hip_atomic_load(&src8[g0],      __ATOMIC_RELAXED, __HIP_MEMORY_SCOPE_AGENT);
        v1 = __hip_atomic_load(&src8[g0 + 64], __ATOMIC_RELAXED, __HIP_MEMORY_SCOPE_AGENT);
        const bool ok = (((uint32_t)v0 & 15u) == tagv) & (((uint32_t)v1 & 15u) == tagv);
        if (__all(ok)) break;
        __builtin_amdgcn_s_sleep(1);
      }
      f32x2* buf = Ss[t & 1];
      buf[pg0] = __builtin_bit_cast(f32x2, v0);
      buf[pg1] = __builtin_bit_cast(f32x2, v1);
      __syncthreads();   // all quarters staged

      // ---- dot: accx/accy[c] += s_pair * A_pair, A read from AGPRs ----
      float accx[8] = {0.f, 0.f, 0.f, 0.f, 0.f, 0.f, 0.f, 0.f};
      float accy[8] = {0.f, 0.f, 0.f, 0.f, 0.f, 0.f, 0.f, 0.f};
#pragma unroll
      for (int k = 0; k < 8; ++k) {
        const f32x2 sv = buf[pidx((k << 6) + l)];
        const float svx = sv.x, svy = sv.y;
#pragma unroll
        for (int c = 0; c < 8; ++c) {
          float ax_, ay_;
          asm volatile("v_accvgpr_read_b32 %0, %1"
                       : "=v"(ax_) : "a"(ar[(k << 4) + (c << 1)]));
          asm volatile("v_accvgpr_read_b32 %0, %1"
                       : "=v"(ay_) : "a"(ar[(k << 4) + (c << 1) + 1]));
          accx[c] = __builtin_fmaf(svx, ax_, accx[c]);
          accy[c] = __builtin_fmaf(svy, ay_, accy[c]);
        }
      }
      float p[8];
#pragma unroll
      for (int c = 0; c < 8; ++c) p[c] = accx[c] + accy[c];

      // ---- reduce-scatter (small offsets first): 10 shuffles total ----
      // lane l ends with the FULL dot for col (l&7), replicated across lane groups.
      const bool b0 = (l & 1) != 0, b1 = (l & 2) != 0, b2 = (l & 4) != 0;
      float r[4];
#pragma unroll
      for (int i = 0; i < 4; ++i) {
        const float keep = b0 ? p[2 * i + 1] : p[2 * i];
        const float send = b0 ? p[2 * i] : p[2 * i + 1];
        r[i] = keep + __shfl_xor(send, 1, 64);
      }
      float q[2];
#pragma unroll
      for (int m = 0; m < 2; ++m) {
        const float keep = b1 ? r[2 * m + 1] : r[2 * m];
        const float send = b1 ? r[2 * m] : r[2 * m + 1];
        q[m] = keep + __shfl_xor(send, 2, 64);
      }
      {
        const float keep = b2 ? q[1] : q[0];
        const float send = b2 ? q[0] : q[1];
        f = keep + __shfl_xor(send, 4, 64);
      }
      f += __shfl_xor(f, 8, 64);
      f += __shfl_xor(f, 16, 64);
      f += __shfl_xor(f, 32, 64);
    }

    const float sv = fast_tanh(f + pu);
    const float val = pg * sv + (1.f - pg) * pi;   // meaningful on l<8 only

    // pack col pairs into one 8B atomic store: low float carries the epoch tag
    const float valn = __shfl_xor(val, 1, 64);
    if ((l < 8) && ((l & 1) == 0)) {
      const uint32_t tagst = (uint32_t)((t & 7) | 8);
      const uint32_t lo = (__builtin_bit_cast(uint32_t, val) & ~15u) | tagst;
      const uint32_t hi = __builtin_bit_cast(uint32_t, valn);
      const unsigned long long pk = ((unsigned long long)hi << 32) | lo;
      __hip_atomic_store(&slice8[(((size_t)t * NBATCH + b) << 9) + ((j0 + l) >> 1)],
                         pk, __ATOMIC_RELAXED, __HIP_MEMORY_SCOPE_AGENT);
    }
    // no drain, no flag: the in-granule tag IS the validity bit.
  }
}

// ---------------- GEMM 3: out = states @ W_out^T + b_out (reads slice[t][b][k]) ----------------
__global__ __launch_bounds__(256) void k_gemm_out(
    const float* __restrict__ S, const float* __restrict__ W,
    const float* __restrict__ bias, float* __restrict__ Y) {
  __shared__ float Xs[16][68];
  __shared__ float Ws[16][68];
  const int tid = threadIdx.x;
  const int m0 = blockIdx.y << 6, n0 = blockIdx.x << 6;
  const int tx = tid & 15, ty = tid >> 4;
  const int lr = tid >> 2, lk = (tid & 3) << 2;
  const int bb_ = m0 >> 12;          // batch (m-block never crosses batch: 4096 % 64 == 0)
  const int t0 = (m0 & 4095) + lr;   // time index of this loader row
  float acc[4][4] = {};
  const float* wp = W + (size_t)(n0 + lr) * D + lk;
  for (int k0 = 0; k0 < D; k0 += 16) {
    const int k = k0 + lk;
    // states(r=b*4096+t, k) lives at slice[(t*8+b)*1024 + k]
    float4 xv = *(const float4*)(S + (((size_t)t0 * NBATCH + bb_) << 10) + k);
    float4 wv = *(const float4*)(wp + k0);
    __syncthreads();
    Xs[lk + 0][lr] = xv.x; Xs[lk + 1][lr] = xv.y; Xs[lk + 2][lr] = xv.z; Xs[lk + 3][lr] = xv.w;
    Ws[lk + 0][lr] = wv.x; Ws[lk + 1][lr] = wv.y; Ws[lk + 2][lr] = wv.z; Ws[lk + 3][lr] = wv.w;
    __syncthreads();
#pragma unroll
    for (int kk = 0; kk < 16; ++kk) {
      float4 av = *(const float4*)&Xs[kk][tx << 2];
      float4 bv = *(const float4*)&Ws[kk][ty << 2];
      const float aa[4] = {av.x, av.y, av.z, av.w};
      const float bb[4] = {bv.x, bv.y, bv.z, bv.w};
#pragma unroll
      for (int i = 0; i < 4; ++i)
#pragma unroll
        for (int jj = 0; jj < 4; ++jj) acc[i][jj] += aa[i] * bb[jj];
    }
  }
  const int nc = n0 + (ty << 2);
#pragma unroll
  for (int i = 0; i < 4; ++i) {
    const int row = m0 + (tx << 2) + i;
    float4 o;
    o.x = acc[i][0] + bias[nc + 0];
    o.y = acc[i][1] + bias[nc + 1];
    o.z = acc[i][2] + bias[nc + 2];
    o.w = acc[i][3] + bias[nc + 3];
    *(float4*)&Y[(size_t)row * D + nc] = o;
  }
}

extern "C" void kernel_launch(void* const* d_in, const int* in_sizes, int n_in,
                              void* d_out, int out_size, void* d_ws, size_t ws_size,
                              hipStream_t stream) {
  const float* x      = (const float*)d_in[0];
  const float* A      = (const float*)d_in[1];
  const float* B      = (const float*)d_in[2];
  const float* W_in   = (const float*)d_in[3];
  const float* b_in   = (const float*)d_in[4];
  const float* W_gate = (const float*)d_in[5];
  const float* b_gate = (const float*)d_in[6];
  const float* W_out  = (const float*)d_in[7];
  const float* b_out  = (const float*)d_in[8];
  float* out = (float*)d_out;
  char* ws = (char*)d_ws;

  uint16_t* gate = (uint16_t*)ws;
  uint16_t* u    = (uint16_t*)(ws + GATE_BYTES);
  float* slice   = (float*)(ws + GATE_BYTES + U_BYTES);

  // Clear stale epoch tags from previous launches (tag nibble 0 is never valid).
  hipMemsetAsync(slice, 0, SLICE_BYTES, stream);

  dim3 gg(D / 64, NROWS / 64);
  // inp parked in d_out (fp32) until k_gemm_out overwrites it.
  k_gemm_in<<<gg, 256, 0, stream>>>(x, W_in, b_in, out);
  k_gemm_gate_u<<<gg, 256, 0, stream>>>(out, W_gate, b_gate, B, gate, u);
  k_scan<<<256, 256, 0, stream>>>(A, out, gate, u, slice);
  k_gemm_out<<<gg, 256, 0, stream>>>(slice, W_out, b_out, out);
}

// Round 5
// 7319.446 us; speedup vs baseline: 1.4617x; 1.4617x over previous
//
#include <hip/hip_runtime.h>
#include <stdint.h>

// MambaBlock: DIM=1024, BATCH=8, SEQ=4096.
//   inp  = x @ W_in^T + b_in            (split-bf16 MFMA -> bf16 hi/lo pair in d_out)
//   gate = sigmoid(inp @ Wg^T + bg)     (split-bf16 MFMA, bf16 out in ws)
//   u    = inp @ B^T                    (split-bf16 MFMA, bf16 out in ws)
//   scan: s_t = g*tanh(s_{t-1}@A^T + u_t) + (1-g)*inp_t   (v4: tagged-granule LLC exchange)
//   out  = states @ W_out^T + b_out     (split-bf16 MFMA, fp32 -> d_out)
//
// Round 5: scan reverted to v4 (v5's AGPR reads = +280cy/step serialized VALU,
// regressed; v4's L1-cached A re-loads were never the bottleneck). The win this
// round is the GEMMs: fp32 vector (no fp32 MFMA on CDNA4) -> split-bf16 MFMA:
//   a = ah + al (ah = truncate-to-bf16, al = rne-bf16(a-ah)), same for b;
//   a*b ~ ah*bh + ah*bl + al*bh (fp32 MFMA accum; dropped al*bl ~ 2^-16 rel).
// 3x bf16-MFMA rate ~ 690 TF effective vs 157 TF fp32 vector.
// Workspace stays 256MB: pre-scan weight hi/lo parked in the slice region
// (memset moved to just before k_scan); W_out hi/lo converted post-scan into
// the dead gate region. inp is produced as bf16 hi/lo halves of d_out, so
// gate_u stages pure bf16 and scan reads pi = hi+lo (2^-17 rel, harmless).

#define D 1024
#define NBATCH 8
#define SEQ 4096
#define NROWS 32768  // NBATCH*SEQ

static constexpr size_t GATE_BYTES  = (size_t)NROWS * D * 2;          // 64 MiB bf16
static constexpr size_t U_BYTES     = (size_t)NROWS * D * 2;          // 64 MiB bf16
static constexpr size_t SLICE_BYTES = (size_t)SEQ * NBATCH * D * 4;   // 128 MiB fp32

typedef float f32x2 __attribute__((ext_vector_type(2)));
typedef float f32x4 __attribute__((ext_vector_type(4)));
typedef short bf16x8 __attribute__((ext_vector_type(8)));
typedef unsigned short u16x4 __attribute__((ext_vector_type(4)));
typedef unsigned short u16x8 __attribute__((ext_vector_type(8)));

#define MFMA16(a, b, c) __builtin_amdgcn_mfma_f32_16x16x32_bf16((a), (b), (c), 0, 0, 0)

__device__ __forceinline__ float bf2f(uint16_t h) {
  uint32_t u = ((uint32_t)h) << 16;
  return __builtin_bit_cast(float, u);
}
__device__ __forceinline__ uint16_t f2bf(float f) {
  uint32_t u = __builtin_bit_cast(uint32_t, f);
  u = u + 0x7fffu + ((u >> 16) & 1u);   // RNE
  return (uint16_t)(u >> 16);
}
// split: h = truncated bf16(x), l = rne-bf16(x - h).  |x-(h+l)| <= 2^-17|x|.
__device__ __forceinline__ void split1(float x, uint16_t& h, uint16_t& l) {
  const uint32_t xb = __builtin_bit_cast(uint32_t, x);
  h = (uint16_t)(xb >> 16);
  const float hr = __builtin_bit_cast(float, xb & 0xffff0000u);
  l = f2bf(x - hr);
}
__device__ __forceinline__ void split4(const float4 v, u16x4& h, u16x4& l) {
  uint16_t h0, l0, h1, l1, h2, l2, h3, l3;
  split1(v.x, h0, l0); split1(v.y, h1, l1);
  split1(v.z, h2, l2); split1(v.w, h3, l3);
  h = u16x4{h0, h1, h2, h3};
  l = u16x4{l0, l1, l2, l3};
}
// branch-free tanh
__device__ __forceinline__ float fast_tanh(float x) {
  const float e = __expf(2.0f * x);
  return 1.0f - 2.0f / (e + 1.0f);
}

// ---------------- fp32 -> bf16 hi/lo converter (1024x1024 per launch) ----------------
__global__ __launch_bounds__(256) void k_cvt(
    const float* __restrict__ S, uint16_t* __restrict__ H, uint16_t* __restrict__ L) {
  const int i = (blockIdx.x * 256 + threadIdx.x) << 2;
  const float4 v = *(const float4*)&S[i];
  u16x4 h, l;
  split4(v, h, l);
  *(u16x4*)&H[i] = h;
  *(u16x4*)&L[i] = l;
}

// ============ MFMA GEMM family: 128x64 block tile, 4 waves x (64x32) ============
// Fragment layout (mfma_f32_16x16x32_bf16, m89-verified):
//   A: lane holds A[lane&15][8*(lane>>4)+i]   (8 bf16 = 16B contiguous k)
//   B: lane holds B[8*(lane>>4)+i][lane&15] = W[lane&15][8*(lane>>4)+i]
//   D: lane reg i = D[4*(lane>>4)+i][lane&15]
// LDS rows padded to 40 bf16 (80B, 16B-aligned): frag reads are ~2-way only.

// ------ GEMM 1: inp = x @ W_in^T + b_in; x fp32 (on-the-fly split), out bf16 h/l ------
__global__ __launch_bounds__(256) void k_gemm_in(
    const float* __restrict__ X, const uint16_t* __restrict__ WhG,
    const uint16_t* __restrict__ WlG, const float* __restrict__ bias,
    uint16_t* __restrict__ Yh, uint16_t* __restrict__ Yl) {
  __shared__ uint16_t XhS[128][40], XlS[128][40];
  __shared__ uint16_t BhS[64][40], BlS[64][40];
  const int tid = threadIdx.x;
  const int w = tid >> 6, l = tid & 63;
  const int n0 = blockIdx.x << 6, m0 = blockIdx.y << 7;
  const int wr = w >> 1, wc = w & 1;
  f32x4 acc[4][2];
#pragma unroll
  for (int mt = 0; mt < 4; ++mt)
#pragma unroll
    for (int nt = 0; nt < 2; ++nt) acc[mt][nt] = f32x4{0.f, 0.f, 0.f, 0.f};

  const int xr = tid >> 3, xc = (tid & 7) << 2;   // X stage: 4 rows (stride 32)
  const int br = tid >> 2, bc = (tid & 3) << 3;   // W stage: 1 row-chunk

  for (int k0 = 0; k0 < D; k0 += 32) {
    float4 xv[4];
#pragma unroll
    for (int q = 0; q < 4; ++q)
      xv[q] = *(const float4*)&X[(size_t)(m0 + xr + (q << 5)) * D + k0 + xc];
    const u16x8 wh = *(const u16x8*)&WhG[(size_t)(n0 + br) * D + k0 + bc];
    const u16x8 wl = *(const u16x8*)&WlG[(size_t)(n0 + br) * D + k0 + bc];
    __syncthreads();
#pragma unroll
    for (int q = 0; q < 4; ++q) {
      u16x4 h, lo;
      split4(xv[q], h, lo);
      *(u16x4*)&XhS[xr + (q << 5)][xc] = h;
      *(u16x4*)&XlS[xr + (q << 5)][xc] = lo;
    }
    *(u16x8*)&BhS[br][bc] = wh;
    *(u16x8*)&BlS[br][bc] = wl;
    __syncthreads();

    bf16x8 ah[4], al[4], bh[2], bl[2];
#pragma unroll
    for (int mt = 0; mt < 4; ++mt) {
      const int r = (wr << 6) + (mt << 4) + (l & 15), s = (l >> 4) << 3;
      ah[mt] = *(const bf16x8*)&XhS[r][s];
      al[mt] = *(const bf16x8*)&XlS[r][s];
    }
#pragma unroll
    for (int nt = 0; nt < 2; ++nt) {
      const int r = (wc << 5) + (nt << 4) + (l & 15), s = (l >> 4) << 3;
      bh[nt] = *(const bf16x8*)&BhS[r][s];
      bl[nt] = *(const bf16x8*)&BlS[r][s];
    }
#pragma unroll
    for (int mt = 0; mt < 4; ++mt)
#pragma unroll
      for (int nt = 0; nt < 2; ++nt) {
        acc[mt][nt] = MFMA16(ah[mt], bh[nt], acc[mt][nt]);
        acc[mt][nt] = MFMA16(ah[mt], bl[nt], acc[mt][nt]);
        acc[mt][nt] = MFMA16(al[mt], bh[nt], acc[mt][nt]);
      }
  }
#pragma unroll
  for (int mt = 0; mt < 4; ++mt)
#pragma unroll
    for (int nt = 0; nt < 2; ++nt) {
      const int col = n0 + (wc << 5) + (nt << 4) + (l & 15);
      const float bv = bias[col];
#pragma unroll
      for (int i = 0; i < 4; ++i) {
        const int row = m0 + (wr << 6) + (mt << 4) + ((l >> 4) << 2) + i;
        uint16_t hh, ll;
        split1(acc[mt][nt][i] + bv, hh, ll);
        Yh[(size_t)row * D + col] = hh;
        Yl[(size_t)row * D + col] = ll;
      }
    }
}

// ------ GEMM 2: gate = sigmoid(inp@Wg^T + bg), u = inp@B^T; all-bf16 staged ------
__global__ __launch_bounds__(256) void k_gemm_gate_u(
    const uint16_t* __restrict__ Ah, const uint16_t* __restrict__ Al,
    const uint16_t* __restrict__ WgH, const uint16_t* __restrict__ WgL,
    const uint16_t* __restrict__ BuH, const uint16_t* __restrict__ BuL,
    const float* __restrict__ bg,
    uint16_t* __restrict__ G, uint16_t* __restrict__ U) {
  __shared__ uint16_t XhS[128][40], XlS[128][40];
  __shared__ uint16_t GhS[64][40], GlS[64][40];
  __shared__ uint16_t UhS[64][40], UlS[64][40];
  const int tid = threadIdx.x;
  const int w = tid >> 6, l = tid & 63;
  const int n0 = blockIdx.x << 6, m0 = blockIdx.y << 7;
  const int wr = w >> 1, wc = w & 1;
  f32x4 accg[4][2], accu[4][2];
#pragma unroll
  for (int mt = 0; mt < 4; ++mt)
#pragma unroll
    for (int nt = 0; nt < 2; ++nt) {
      accg[mt][nt] = f32x4{0.f, 0.f, 0.f, 0.f};
      accu[mt][nt] = f32x4{0.f, 0.f, 0.f, 0.f};
    }
  const int ar = tid >> 2, ac = (tid & 3) << 3;

  for (int k0 = 0; k0 < D; k0 += 32) {
    u16x8 xh[2], xl[2];
#pragma unroll
    for (int q = 0; q < 2; ++q) {
      xh[q] = *(const u16x8*)&Ah[(size_t)(m0 + ar + (q << 6)) * D + k0 + ac];
      xl[q] = *(const u16x8*)&Al[(size_t)(m0 + ar + (q << 6)) * D + k0 + ac];
    }
    const u16x8 gh = *(const u16x8*)&WgH[(size_t)(n0 + ar) * D + k0 + ac];
    const u16x8 gl = *(const u16x8*)&WgL[(size_t)(n0 + ar) * D + k0 + ac];
    const u16x8 uh = *(const u16x8*)&BuH[(size_t)(n0 + ar) * D + k0 + ac];
    const u16x8 ul = *(const u16x8*)&BuL[(size_t)(n0 + ar) * D + k0 + ac];
    __syncthreads();
#pragma unroll
    for (int q = 0; q < 2; ++q) {
      *(u16x8*)&XhS[ar + (q << 6)][ac] = xh[q];
      *(u16x8*)&XlS[ar + (q << 6)][ac] = xl[q];
    }
    *(u16x8*)&GhS[ar][ac] = gh;
    *(u16x8*)&GlS[ar][ac] = gl;
    *(u16x8*)&UhS[ar][ac] = uh;
    *(u16x8*)&UlS[ar][ac] = ul;
    __syncthreads();

    bf16x8 ah[4], al[4];
#pragma unroll
    for (int mt = 0; mt < 4; ++mt) {
      const int r = (wr << 6) + (mt << 4) + (l & 15), s = (l >> 4) << 3;
      ah[mt] = *(const bf16x8*)&XhS[r][s];
      al[mt] = *(const bf16x8*)&XlS[r][s];
    }
#pragma unroll
    for (int nt = 0; nt < 2; ++nt) {
      const int r = (wc << 5) + (nt << 4) + (l & 15), s = (l >> 4) << 3;
      const bf16x8 bgh = *(const bf16x8*)&GhS[r][s];
      const bf16x8 bgl = *(const bf16x8*)&GlS[r][s];
      const bf16x8 buh = *(const bf16x8*)&UhS[r][s];
      const bf16x8 bul = *(const bf16x8*)&UlS[r][s];
#pragma unroll
      for (int mt = 0; mt < 4; ++mt) {
        accg[mt][nt] = MFMA16(ah[mt], bgh, accg[mt][nt]);
        accg[mt][nt] = MFMA16(ah[mt], bgl, accg[mt][nt]);
        accg[mt][nt] = MFMA16(al[mt], bgh, accg[mt][nt]);
        accu[mt][nt] = MFMA16(ah[mt], buh, accu[mt][nt]);
        accu[mt][nt] = MFMA16(ah[mt], bul, accu[mt][nt]);
        accu[mt][nt] = MFMA16(al[mt], buh, accu[mt][nt]);
      }
    }
  }
#pragma unroll
  for (int mt = 0; mt < 4; ++mt)
#pragma unroll
    for (int nt = 0; nt < 2; ++nt) {
      const int col = n0 + (wc << 5) + (nt << 4) + (l & 15);
      const float bv = bg[col];
#pragma unroll
      for (int i = 0; i < 4; ++i) {
        const int row = m0 + (wr << 6) + (mt << 4) + ((l >> 4) << 2) + i;
        const float z = accg[mt][nt][i] + bv;
        G[(size_t)row * D + col] = f2bf(1.0f / (1.0f + __expf(-z)));
        U[(size_t)row * D + col] = f2bf(accu[mt][nt][i]);
      }
    }
}

// ------ GEMM 3: out = states @ W_out^T + b_out; slice fp32 (on-the-fly split) ------
__global__ __launch_bounds__(256) void k_gemm_out(
    const float* __restrict__ S, const uint16_t* __restrict__ WhG,
    const uint16_t* __restrict__ WlG, const float* __restrict__ bias,
    float* __restrict__ Y) {
  __shared__ uint16_t XhS[128][40], XlS[128][40];
  __shared__ uint16_t BhS[64][40], BlS[64][40];
  const int tid = threadIdx.x;
  const int w = tid >> 6, l = tid & 63;
  const int n0 = blockIdx.x << 6, m0 = blockIdx.y << 7;
  const int wr = w >> 1, wc = w & 1;
  const int bb_ = m0 >> 12;        // batch; m-block never crosses batch (4096%128==0)
  f32x4 acc[4][2];
#pragma unroll
  for (int mt = 0; mt < 4; ++mt)
#pragma unroll
    for (int nt = 0; nt < 2; ++nt) acc[mt][nt] = f32x4{0.f, 0.f, 0.f, 0.f};

  const int xr = tid >> 3, xc = (tid & 7) << 2;
  const int br = tid >> 2, bc = (tid & 3) << 3;

  for (int k0 = 0; k0 < D; k0 += 32) {
    float4 xv[4];
#pragma unroll
    for (int q = 0; q < 4; ++q) {
      const int trow = (m0 & 4095) + xr + (q << 5);
      // states(r=b*4096+t, k) lives at slice[(t*8+b)*1024 + k]
      xv[q] = *(const float4*)&S[(((size_t)trow * NBATCH + bb_) << 10) + k0 + xc];
    }
    const u16x8 wh = *(const u16x8*)&WhG[(size_t)(n0 + br) * D + k0 + bc];
    const u16x8 wl = *(const u16x8*)&WlG[(size_t)(n0 + br) * D + k0 + bc];
    __syncthreads();
#pragma unroll
    for (int q = 0; q < 4; ++q) {
      u16x4 h, lo;
      split4(xv[q], h, lo);
      *(u16x4*)&XhS[xr + (q << 5)][xc] = h;
      *(u16x4*)&XlS[xr + (q << 5)][xc] = lo;
    }
    *(u16x8*)&BhS[br][bc] = wh;
    *(u16x8*)&BlS[br][bc] = wl;
    __syncthreads();

    bf16x8 ah[4], al[4], bh[2], bl[2];
#pragma unroll
    for (int mt = 0; mt < 4; ++mt) {
      const int r = (wr << 6) + (mt << 4) + (l & 15), s = (l >> 4) << 3;
      ah[mt] = *(const bf16x8*)&XhS[r][s];
      al[mt] = *(const bf16x8*)&XlS[r][s];
    }
#pragma unroll
    for (int nt = 0; nt < 2; ++nt) {
      const int r = (wc << 5) + (nt << 4) + (l & 15), s = (l >> 4) << 3;
      bh[nt] = *(const bf16x8*)&BhS[r][s];
      bl[nt] = *(const bf16x8*)&BlS[r][s];
    }
#pragma unroll
    for (int mt = 0; mt < 4; ++mt)
#pragma unroll
      for (int nt = 0; nt < 2; ++nt) {
        acc[mt][nt] = MFMA16(ah[mt], bh[nt], acc[mt][nt]);
        acc[mt][nt] = MFMA16(ah[mt], bl[nt], acc[mt][nt]);
        acc[mt][nt] = MFMA16(al[mt], bh[nt], acc[mt][nt]);
      }
  }
#pragma unroll
  for (int mt = 0; mt < 4; ++mt)
#pragma unroll
    for (int nt = 0; nt < 2; ++nt) {
      const int col = n0 + (wc << 5) + (nt << 4) + (l & 15);
      const float bv = bias[col];
#pragma unroll
      for (int i = 0; i < 4; ++i) {
        const int row = m0 + (wr << 6) + (mt << 4) + ((l >> 4) << 2) + i;
        Y[(size_t)row * D + col] = acc[mt][nt][i] + bv;
      }
    }
}

// ---------------- Scan v4 (reverted best): cooperative poll + LDS broadcast ----------------
__device__ __forceinline__ int pidx(int g) { return g + (g >> 4); }

__global__ __launch_bounds__(256, 1)
__attribute__((amdgpu_waves_per_eu(1, 1)))
void k_scan(
    const float* __restrict__ A,
    const uint16_t* __restrict__ inph, const uint16_t* __restrict__ inpl,
    const uint16_t* __restrict__ gate, const uint16_t* __restrict__ u,
    float* __restrict__ slice) {
  __shared__ f32x2 Ss[2][544];   // 512 granules + pad, double-buffered (8.7 KB)
  const int tid = threadIdx.x;
  const int w = tid >> 6, l = tid & 63;
  const int b = blockIdx.x & 7;        // batch: XCD-local (block i -> XCD i%8)
  const int widx = blockIdx.x >> 3;    // 0..31 within batch
  const int j0 = (widx << 5) + (w << 3);  // wave's 8 output cols

  f32x2 Areg[8][8];
#pragma unroll
  for (int c = 0; c < 8; ++c)
#pragma unroll
    for (int k = 0; k < 8; ++k) {
      const float2 t2 = *(const float2*)&A[(size_t)(j0 + c) * D + (k << 7) + (l << 1)];
      Areg[c][k] = f32x2{t2.x, t2.y};
    }
#pragma unroll
  for (int c = 0; c < 8; ++c)
#pragma unroll
    for (int k = 0; k < 8; ++k)
      asm volatile("" : "+v"(Areg[c][k].x), "+v"(Areg[c][k].y));

  unsigned long long* slice8 = (unsigned long long*)slice;
  const int jc = j0 + l;               // valid for l<8: lane's output column
  const int g0 = (w << 7) + l;         // wave's poll quarter: granules g0, g0+64
  const int pg0 = pidx(g0), pg1 = pidx(g0 + 64);

  for (int t = 0; t < SEQ; ++t) {
    float pg = 0.f, pu = 0.f, pi = 0.f;
    if (l < 8) {
      const size_t ridx = ((size_t)(b << 12) + t) * D + jc;
      pg = bf2f(gate[ridx]);
      pu = bf2f(u[ridx]);
      pi = bf2f(inph[ridx]) + bf2f(inpl[ridx]);
    }
    asm volatile("" : "+v"(pg), "+v"(pu), "+v"(pi));

    float f = 0.f;
    if (t > 0) {
      const unsigned long long* src8 =
          slice8 + (((size_t)(t - 1) * NBATCH + b) << 9);
      const uint32_t tagv = (uint32_t)(((t - 1) & 7) | 8);
      unsigned long long v0, v1;
      while (true) {
        v0 = __hip_atomic_load(&src8[g0],      __ATOMIC_RELAXED, __HIP_MEMORY_SCOPE_AGENT);
        v1 = __hip_atomic_load(&src8[g0 + 64], __ATOMIC_RELAXED, __HIP_MEMORY_SCOPE_AGENT);
        const bool ok = (((uint32_t)v0 & 15u) == tagv) & (((uint32_t)v1 & 15u) == tagv);
        if (__all(ok)) break;
        __builtin_amdgcn_s_sleep(1);
      }
      f32x2* buf = Ss[t & 1];
      buf[pg0] = __builtin_bit_cast(f32x2, v0);
      buf[pg1] = __builtin_bit_cast(f32x2, v1);
      __syncthreads();

      f32x2 acc[8];
#pragma unroll
      for (int c = 0; c < 8; ++c) acc[c] = f32x2{0.f, 0.f};
#pragma unroll
      for (int k = 0; k < 8; ++k) {
        const f32x2 sv = buf[pidx((k << 6) + l)];
#pragma unroll
        for (int c = 0; c < 8; ++c) acc[c] += sv * Areg[c][k];
      }
      float p[8];
#pragma unroll
      for (int c = 0; c < 8; ++c) p[c] = acc[c].x + acc[c].y;

      const bool b0 = (l & 1) != 0, b1 = (l & 2) != 0, b2 = (l & 4) != 0;
      float r[4];
#pragma unroll
      for (int i = 0; i < 4; ++i) {
        const float keep = b0 ? p[2 * i + 1] : p[2 * i];
        const float send = b0 ? p[2 * i] : p[2 * i + 1];
        r[i] = keep + __shfl_xor(send, 1, 64);
      }
      float q[2];
#pragma unroll
      for (int m = 0; m < 2; ++m) {
        const float keep = b1 ? r[2 * m + 1] : r[2 * m];
        const float send = b1 ? r[2 * m] : r[2 * m + 1];
        q[m] = keep + __shfl_xor(send, 2, 64);
      }
      {
        const float keep = b2 ? q[1] : q[0];
        const float send = b2 ? q[0] : q[1];
        f = keep + __shfl_xor(send, 4, 64);
      }
      f += __shfl_xor(f, 8, 64);
      f += __shfl_xor(f, 16, 64);
      f += __shfl_xor(f, 32, 64);
    }

    const float sv = fast_tanh(f + pu);
    const float val = pg * sv + (1.f - pg) * pi;   // meaningful on l<8 only

    const float valn = __shfl_xor(val, 1, 64);
    if ((l < 8) && ((l & 1) == 0)) {
      const uint32_t tagst = (uint32_t)((t & 7) | 8);
      const uint32_t lo = (__builtin_bit_cast(uint32_t, val) & ~15u) | tagst;
      const uint32_t hi = __builtin_bit_cast(uint32_t, valn);
      const unsigned long long pk = ((unsigned long long)hi << 32) | lo;
      __hip_atomic_store(&slice8[(((size_t)t * NBATCH + b) << 9) + ((j0 + l) >> 1)],
                         pk, __ATOMIC_RELAXED, __HIP_MEMORY_SCOPE_AGENT);
    }
  }
}

extern "C" void kernel_launch(void* const* d_in, const int* in_sizes, int n_in,
                              void* d_out, int out_size, void* d_ws, size_t ws_size,
                              hipStream_t stream) {
  const float* x      = (const float*)d_in[0];
  const float* A      = (const float*)d_in[1];
  const float* B      = (const float*)d_in[2];
  const float* W_in   = (const float*)d_in[3];
  const float* b_in   = (const float*)d_in[4];
  const float* W_gate = (const float*)d_in[5];
  const float* b_gate = (const float*)d_in[6];
  const float* W_out  = (const float*)d_in[7];
  const float* b_out  = (const float*)d_in[8];
  float* out = (float*)d_out;
  char* ws = (char*)d_ws;

  uint16_t* gateB = (uint16_t*)ws;
  uint16_t* uB    = (uint16_t*)(ws + GATE_BYTES);
  float* slice    = (float*)(ws + GATE_BYTES + U_BYTES);

  // inp hi/lo pair parked in d_out halves (scan + gate_u consume; gemm_out overwrites).
  uint16_t* inph = (uint16_t*)d_out;
  uint16_t* inpl = inph + (size_t)NROWS * D;

  // Pre-scan weight hi/lo parked at the START of the slice region (slice is
  // memset only AFTER gate_u); W_out hi/lo converted post-scan into the dead
  // gate region. Workspace stays at 256 MB.
  uint16_t* wslab = (uint16_t*)slice;
  uint16_t* winh = wslab + 0 * 1048576;
  uint16_t* winl = wslab + 1 * 1048576;
  uint16_t* wgh  = wslab + 2 * 1048576;
  uint16_t* wgl  = wslab + 3 * 1048576;
  uint16_t* buh  = wslab + 4 * 1048576;
  uint16_t* bul  = wslab + 5 * 1048576;
  uint16_t* woh  = (uint16_t*)ws;
  uint16_t* wol  = (uint16_t*)ws + 1048576;

  dim3 gg(D / 64, NROWS / 128);
  k_cvt<<<1024, 256, 0, stream>>>(W_in, winh, winl);
  k_cvt<<<1024, 256, 0, stream>>>(W_gate, wgh, wgl);
  k_cvt<<<1024, 256, 0, stream>>>(B, buh, bul);
  k_gemm_in<<<gg, 256, 0, stream>>>(x, winh, winl, b_in, inph, inpl);
  k_gemm_gate_u<<<gg, 256, 0, stream>>>(inph, inpl, wgh, wgl, buh, bul, b_gate, gateB, uB);
  // Clear stale epoch tags (also wipes the parked weights, now consumed).
  hipMemsetAsync(slice, 0, SLICE_BYTES, stream);
  k_scan<<<256, 256, 0, stream>>>(A, inph, inpl, gateB, uB, slice);
  k_cvt<<<1024, 256, 0, stream>>>(W_out, woh, wol);   // gate region is dead now
  k_gemm_out<<<gg, 256, 0, stream>>>(slice, woh, wol, b_out, out);
}